// Round 8
// baseline (1181.607 us; speedup 1.0000x reference)
//
#include <hip/hip_runtime.h>
#include <hip/hip_cooperative_groups.h>

namespace cg = cooperative_groups;

#define D 128
#define BN_EPS 1e-5f
#define ELLW 64             // max degree slots (Poisson(12.8): P(deg>=64) ~ 1e-24)

typedef __bf16 bf16_t;
typedef __bf16 bf16x8 __attribute__((ext_vector_type(8)));
typedef __bf16 bf16x4 __attribute__((ext_vector_type(4)));
typedef __bf16 bf16x2 __attribute__((ext_vector_type(2)));
typedef float floatx4 __attribute__((ext_vector_type(4)));

// ===========================================================================
// Entire 3-layer GIN in ONE cooperative kernel. All phases are grid-stride
// (correct for ANY grid size; host clamps grid to the queried co-residency).
//  P0: zero deg/stats, x fp32->bf16, swizzle W1/W2 into MFMA B-frag order
//  P1: ELL build (atomic bump per dst; ushort src indices)
//  per layer:
//   P2: aggregate z = h + sum_nbr h    (one wave per node)
//   P3: Y = z @ W1 + b1 (MFMA), BN column stats -> global atomics (Y dropped)
//   P4: BN coeffs; RECOMPUTE Y (bit-identical MFMA), P=relu(a*Y+b),
//       LDS transpose to A-layout, out = P @ W2 + b2
// ===========================================================================
__global__ __launch_bounds__(256, 4) void gin_all(
    const float* __restrict__ x, const float* __restrict__ W1,
    const float* __restrict__ b1, const float* __restrict__ gamma,
    const float* __restrict__ beta, const float* __restrict__ W2,
    const float* __restrict__ b2, const int* __restrict__ ei,
    float* __restrict__ out, bf16_t* __restrict__ hb, bf16_t* __restrict__ zb,
    bf16_t* __restrict__ Wsw, unsigned short* __restrict__ ell,
    int* __restrict__ deg, float* __restrict__ stats, int N, int E) {
  cg::grid_group grid = cg::this_grid();
  __shared__ bf16_t T[64][136];      // P-tile transpose (within-P4 only)
  __shared__ float sred[256];
  __shared__ float abL[256];

  const int t = threadIdx.x;
  const int gtid = blockIdx.x * 256 + t;
  const int gsz = gridDim.x * 256;
  const int wv = t >> 6;
  const int lane = t & 63;
  const int l15 = lane & 15;
  const int quad = lane >> 4;
  const int* src = ei;
  const int* dst = ei + E;
  const int n4 = N * (D / 4);

  // ---------------- P0: prep ----------------
  for (int i = gtid; i < n4; i += gsz) {
    float4 v = ((const float4*)x)[i];
    bf16x4 p;
    p[0] = (bf16_t)v.x; p[1] = (bf16_t)v.y; p[2] = (bf16_t)v.z; p[3] = (bf16_t)v.w;
    *(bf16x4*)(hb + (size_t)4 * i) = p;
  }
  for (int i = gtid; i < N; i += gsz) deg[i] = 0;
  if (gtid < 768) stats[gtid] = 0.f;
  for (int i = gtid; i < 6 * 16384; i += gsz) {
    int mat = i >> 14;
    int kn = i & 16383;
    int k = kn >> 7;
    int n = kn & 127;
    const float* Wm = (mat < 3) ? (W1 + (size_t)mat * 16384)
                                : (W2 + (size_t)(mat - 3) * 16384);
    float v = Wm[kn];
    int f = ((n >> 4) << 2) | (k >> 5);
    int ln = (((k >> 3) & 3) << 4) | (n & 15);
    int j = k & 7;
    Wsw[(size_t)mat * 16384 + ((f << 6) + ln) * 8 + j] = (bf16_t)v;
  }
  grid.sync();

  // ---------------- P1: ELL build ----------------
  for (int e = gtid; e < E; e += gsz) {
    int d = dst[e];
    int slot = atomicAdd(&deg[d], 1);
    if (slot < ELLW) ell[(size_t)d * ELLW + slot] = (unsigned short)src[e];
  }
  grid.sync();

  const int nGroups = (N + 3) >> 2;
  const int nStrips = (N + 15) >> 4;
  const int nTasks = (nStrips + 3) >> 2;
  const float invN = 1.f / (float)N;

  for (int layer = 0; layer < 3; ++layer) {
    const bf16_t* Ws1 = Wsw + (size_t)layer * 16384;
    const bf16_t* Ws2 = Wsw + (size_t)(layer + 3) * 16384;
    float* st = stats + (size_t)layer * 256;
    const float* b1l = b1 + (size_t)layer * D;
    const float* b2l = b2 + (size_t)layer * D;
    const float* gl  = gamma + (size_t)layer * D;
    const float* btl = beta + (size_t)layer * D;

    // ---------------- P2: aggregate ----------------
    {
      const int off = lane << 1;
      for (int g = blockIdx.x; g < nGroups; g += gridDim.x) {
        int node = g * 4 + wv;
        if (node < N) {
          int dg = deg[node]; if (dg > ELLW) dg = ELLW;
          const unsigned short* nb = ell + (size_t)node * ELLW;
          bf16x2 sv = *(const bf16x2*)(hb + (size_t)node * D + off);
          float a0x = (float)sv[0], a0y = (float)sv[1];
          float a1x = 0.f, a1y = 0.f, a2x = 0.f, a2y = 0.f, a3x = 0.f, a3y = 0.f;
          int e = 0;
          for (; e + 4 <= dg; e += 4) {
            ushort4 i4 = *(const ushort4*)(nb + e);
            bf16x2 v0 = *(const bf16x2*)(hb + (size_t)i4.x * D + off);
            bf16x2 v1 = *(const bf16x2*)(hb + (size_t)i4.y * D + off);
            bf16x2 v2 = *(const bf16x2*)(hb + (size_t)i4.z * D + off);
            bf16x2 v3 = *(const bf16x2*)(hb + (size_t)i4.w * D + off);
            a0x += (float)v0[0]; a0y += (float)v0[1];
            a1x += (float)v1[0]; a1y += (float)v1[1];
            a2x += (float)v2[0]; a2y += (float)v2[1];
            a3x += (float)v3[0]; a3y += (float)v3[1];
          }
          for (; e < dg; ++e) {
            bf16x2 v = *(const bf16x2*)(hb + (size_t)nb[e] * D + off);
            a0x += (float)v[0]; a0y += (float)v[1];
          }
          a0x += a1x + a2x + a3x;
          a0y += a1y + a2y + a3y;
          bf16x2 o;
          o[0] = (bf16_t)a0x; o[1] = (bf16_t)a0y;
          *(bf16x2*)(zb + (size_t)node * D + off) = o;
        }
      }
    }
    grid.sync();

    // ---------------- P3: GEMM1 -> BN stats only ----------------
    sred[t] = 0.f;
    float sAcc[8], qAcc[8];
#pragma unroll
    for (int nt = 0; nt < 8; ++nt) { sAcc[nt] = 0.f; qAcc[nt] = 0.f; }

    for (int task = blockIdx.x; task < nTasks; task += gridDim.x) {
      const int strip = task * 4 + wv;
      if (strip < nStrips) {
        bf16x8 a[4];
        const int row = strip * 16 + l15;
        if (row < N) {
#pragma unroll
          for (int kc = 0; kc < 4; ++kc)
            a[kc] = *(const bf16x8*)(zb + (size_t)row * D + kc * 32 + quad * 8);
        } else {
#pragma unroll
          for (int kc = 0; kc < 4; ++kc)
#pragma unroll
            for (int j = 0; j < 8; ++j) a[kc][j] = (bf16_t)0.f;
        }
        floatx4 acc[8];
#pragma unroll
        for (int nt = 0; nt < 8; ++nt) {
          float bv = b1l[nt * 16 + l15];
          acc[nt] = (floatx4){bv, bv, bv, bv};
        }
#pragma unroll
        for (int nt = 0; nt < 8; ++nt) {
#pragma unroll
          for (int kc = 0; kc < 4; ++kc) {
            bf16x8 b = *(const bf16x8*)(Ws1 + (size_t)((nt * 4 + kc) * 64 + lane) * 8);
            acc[nt] = __builtin_amdgcn_mfma_f32_16x16x32_bf16(a[kc], b, acc[nt], 0, 0, 0);
          }
        }
        const int rowBase = strip * 16 + quad * 4;
#pragma unroll
        for (int nt = 0; nt < 8; ++nt) {
#pragma unroll
          for (int r = 0; r < 4; ++r) {
            if (rowBase + r < N) {
              float v = acc[nt][r];
              sAcc[nt] += v; qAcc[nt] += v * v;
            }
          }
        }
      }
    }
    __syncthreads();   // sred zeroed by all
#pragma unroll
    for (int nt = 0; nt < 8; ++nt) {
      float s = sAcc[nt], q = qAcc[nt];
      s += __shfl_xor(s, 16); s += __shfl_xor(s, 32);
      q += __shfl_xor(q, 16); q += __shfl_xor(q, 32);
      if (quad == 0) {
        int c = nt * 16 + l15;
        atomicAdd(&sred[c], s);
        atomicAdd(&sred[128 + c], q);
      }
    }
    __syncthreads();
    atomicAdd(&st[t], sred[t]);
    grid.sync();

    // ---------------- P4: BN coeffs + recompute Y + GEMM2 ----------------
    if (t < 128) {
      float mu = st[t] * invN;
      float var = fmaxf(st[128 + t] * invN - mu * mu, 0.f);
      float a = gl[t] * rsqrtf(var + BN_EPS);
      abL[t] = a;
      abL[128 + t] = btl[t] - mu * a;
    }
    __syncthreads();

    for (int task = blockIdx.x; task < nTasks; task += gridDim.x) {
      const int strip = task * 4 + wv;
      const bool active = strip < nStrips;
      if (active) {
        bf16x8 a[4];
        const int row = strip * 16 + l15;
        if (row < N) {
#pragma unroll
          for (int kc = 0; kc < 4; ++kc)
            a[kc] = *(const bf16x8*)(zb + (size_t)row * D + kc * 32 + quad * 8);
        } else {
#pragma unroll
          for (int kc = 0; kc < 4; ++kc)
#pragma unroll
            for (int j = 0; j < 8; ++j) a[kc][j] = (bf16_t)0.f;
        }
        floatx4 acc[8];
#pragma unroll
        for (int nt = 0; nt < 8; ++nt) {
          float bv = b1l[nt * 16 + l15];
          acc[nt] = (floatx4){bv, bv, bv, bv};
        }
#pragma unroll
        for (int nt = 0; nt < 8; ++nt) {
#pragma unroll
          for (int kc = 0; kc < 4; ++kc) {
            bf16x8 b = *(const bf16x8*)(Ws1 + (size_t)((nt * 4 + kc) * 64 + lane) * 8);
            acc[nt] = __builtin_amdgcn_mfma_f32_16x16x32_bf16(a[kc], b, acc[nt], 0, 0, 0);
          }
        }
        // P = relu(a*Y+b) in C-layout -> LDS transpose tile
        const int lr = wv * 16 + quad * 4;
#pragma unroll
        for (int nt = 0; nt < 8; ++nt) {
          int c = nt * 16 + l15;
          float av = abL[c], bv = abL[128 + c];
#pragma unroll
          for (int r = 0; r < 4; ++r)
            T[lr + r][c] = (bf16_t)fmaxf(fmaf(acc[nt][r], av, bv), 0.f);
        }
      }
      __syncthreads();
      if (active) {
        bf16x8 a2[4];
#pragma unroll
        for (int kc = 0; kc < 4; ++kc)
          a2[kc] = *(const bf16x8*)&T[wv * 16 + l15][kc * 32 + quad * 8];

        floatx4 acc2[8];
#pragma unroll
        for (int nt = 0; nt < 8; ++nt) {
          float bv = b2l[nt * 16 + l15];
          acc2[nt] = (floatx4){bv, bv, bv, bv};
        }
#pragma unroll
        for (int nt = 0; nt < 8; ++nt) {
#pragma unroll
          for (int kc = 0; kc < 4; ++kc) {
            bf16x8 b = *(const bf16x8*)(Ws2 + (size_t)((nt * 4 + kc) * 64 + lane) * 8);
            acc2[nt] = __builtin_amdgcn_mfma_f32_16x16x32_bf16(a2[kc], b, acc2[nt], 0, 0, 0);
          }
        }
        const int rowBase = strip * 16 + quad * 4;
        if (layer == 2) {
#pragma unroll
          for (int nt = 0; nt < 8; ++nt) {
            int c = nt * 16 + l15;
#pragma unroll
            for (int r = 0; r < 4; ++r) {
              int row = rowBase + r;
              if (row < N) out[(size_t)row * D + c] = acc2[nt][r];
            }
          }
        } else {
#pragma unroll
          for (int nt = 0; nt < 8; ++nt) {
            int c = nt * 16 + l15;
#pragma unroll
            for (int r = 0; r < 4; ++r) {
              int row = rowBase + r;
              if (row < N) hb[(size_t)row * D + c] = (bf16_t)fmaxf(acc2[nt][r], 0.f);
            }
          }
        }
      }
      __syncthreads();   // protect T before next task iteration
    }
    if (layer < 2) grid.sync();
  }
}

// ===========================================================================
extern "C" void kernel_launch(void* const* d_in, const int* in_sizes, int n_in,
                              void* d_out, int out_size, void* d_ws, size_t ws_size,
                              hipStream_t stream) {
  const float* x     = (const float*)d_in[0];
  const float* W1    = (const float*)d_in[1];
  const float* b1    = (const float*)d_in[2];
  const float* gamma = (const float*)d_in[3];
  const float* beta  = (const float*)d_in[4];
  const float* W2    = (const float*)d_in[5];
  const float* b2    = (const float*)d_in[6];
  const int*   ei    = (const int*)d_in[7];

  int N = in_sizes[0] / D;
  int E = in_sizes[7] / 2;
  float* out = (float*)d_out;

  char* ws = (char*)d_ws;
  size_t bufBytes = (size_t)N * D * sizeof(bf16_t);        // 12.8 MB
  bf16_t* hb   = (bf16_t*)ws;
  bf16_t* zb   = (bf16_t*)(ws + bufBytes);
  unsigned short* ell = (unsigned short*)(ws + 2 * bufBytes);       // N*64 ushort
  int*    deg  = (int*)(ws + 2 * bufBytes + (size_t)N * ELLW * 2);  // N ints
  float*  stats = (float*)((char*)deg + (size_t)N * sizeof(int));   // 768 floats
  bf16_t* Wsw  = (bf16_t*)((char*)stats + 768 * sizeof(float));     // 6*16384 bf16

  // Grid-size-agnostic kernel: clamp grid to queried co-residency so the
  // cooperative launch cannot be rejected. (Pure query — capture-safe.)
  int blocksPerCU = 0;
  hipOccupancyMaxActiveBlocksPerMultiprocessor(&blocksPerCU,
                                               (const void*)gin_all, 256, 0);
  if (blocksPerCU < 1) blocksPerCU = 1;
  int grid = blocksPerCU * 256;        // 256 CUs on MI355X
  if (grid > 768) grid = 768;

  void* args[] = {&x, &W1, &b1, &gamma, &beta, &W2, &b2, &ei,
                  &out, &hb, &zb, &Wsw, &ell, &deg, &stats, &N, &E};
  hipLaunchCooperativeKernel((const void*)gin_all, dim3(grid), dim3(256),
                             args, 0, stream);
}

// Round 10
// 734.566 us; speedup vs baseline: 1.6086x; 1.6086x over previous
//
#include <hip/hip_runtime.h>
#include <hip/hip_cooperative_groups.h>

namespace cg = cooperative_groups;

#define D 128
#define BN_EPS 1e-5f
#define ELLW 64             // max degree slots (Poisson(12.8): P(deg>=64) ~ 1e-24)

typedef __bf16 bf16_t;
typedef __bf16 bf16x8 __attribute__((ext_vector_type(8)));
typedef __bf16 bf16x4 __attribute__((ext_vector_type(4)));
typedef __bf16 bf16x2 __attribute__((ext_vector_type(2)));
typedef float floatx4 __attribute__((ext_vector_type(4)));

// ===========================================================================
// Cooperative: prep (x->bf16, weight swizzle, zero deg/stats) -> sync -> ELL
// Streaming phases only — fine at co-resident grid sizes.
// ===========================================================================
__global__ __launch_bounds__(256) void prep_ell(
    const float* __restrict__ x, const float* __restrict__ W1,
    const float* __restrict__ W2, const int* __restrict__ ei,
    bf16_t* __restrict__ hb, bf16_t* __restrict__ Wsw,
    unsigned short* __restrict__ ell, int* __restrict__ deg,
    float* __restrict__ stats, int N, int E) {
  cg::grid_group grid = cg::this_grid();
  const int gtid = blockIdx.x * 256 + threadIdx.x;
  const int gsz = gridDim.x * 256;
  const int n4 = N * (D / 4);
  const int* src = ei;
  const int* dst = ei + E;

  for (int i = gtid; i < n4; i += gsz) {
    float4 v = ((const float4*)x)[i];
    bf16x4 p;
    p[0] = (bf16_t)v.x; p[1] = (bf16_t)v.y; p[2] = (bf16_t)v.z; p[3] = (bf16_t)v.w;
    *(bf16x4*)(hb + (size_t)4 * i) = p;
  }
  for (int i = gtid; i < N; i += gsz) deg[i] = 0;
  if (gtid < 768) stats[gtid] = 0.f;
  for (int i = gtid; i < 6 * 16384; i += gsz) {
    // B-frag order: lane = quad*16 + (n&15) holds B[k=kc*32+quad*8+j][n]
    int mat = i >> 14;
    int kn = i & 16383;
    int k = kn >> 7;
    int n = kn & 127;
    const float* Wm = (mat < 3) ? (W1 + (size_t)mat * 16384)
                                : (W2 + (size_t)(mat - 3) * 16384);
    float v = Wm[kn];
    int f = ((n >> 4) << 2) | (k >> 5);
    int ln = (((k >> 3) & 3) << 4) | (n & 15);
    int j = k & 7;
    Wsw[(size_t)mat * 16384 + ((f << 6) + ln) * 8 + j] = (bf16_t)v;
  }
  grid.sync();

  for (int e = gtid; e < E; e += gsz) {
    int d = dst[e];
    int slot = atomicAdd(&deg[d], 1);
    if (slot < ELLW) ell[(size_t)d * ELLW + slot] = (unsigned short)src[e];
  }
}

// ===========================================================================
// Regular launch, one wave per node (12500 blocks): needs oversubscription.
// z[v] = h[v] + sum_{u in N(v)} h[u]; bf16x2/lane, fp32 accum.
// ===========================================================================
__global__ __launch_bounds__(256) void aggregate(
    const bf16_t* __restrict__ h, bf16_t* __restrict__ z,
    const unsigned short* __restrict__ ell, const int* __restrict__ deg,
    int Nn) {
  int node = blockIdx.x * 4 + (threadIdx.x >> 6);
  if (node >= Nn) return;
  int lane = threadIdx.x & 63;
  int off = lane << 1;
  int dg = deg[node]; if (dg > ELLW) dg = ELLW;
  const unsigned short* nb = ell + (size_t)node * ELLW;

  bf16x2 sv = *(const bf16x2*)(h + (size_t)node * D + off);
  float a0x = (float)sv[0], a0y = (float)sv[1];
  float a1x = 0.f, a1y = 0.f, a2x = 0.f, a2y = 0.f, a3x = 0.f, a3y = 0.f;
  int e = 0;
  for (; e + 4 <= dg; e += 4) {
    ushort4 i4 = *(const ushort4*)(nb + e);
    bf16x2 v0 = *(const bf16x2*)(h + (size_t)i4.x * D + off);
    bf16x2 v1 = *(const bf16x2*)(h + (size_t)i4.y * D + off);
    bf16x2 v2 = *(const bf16x2*)(h + (size_t)i4.z * D + off);
    bf16x2 v3 = *(const bf16x2*)(h + (size_t)i4.w * D + off);
    a0x += (float)v0[0]; a0y += (float)v0[1];
    a1x += (float)v1[0]; a1y += (float)v1[1];
    a2x += (float)v2[0]; a2y += (float)v2[1];
    a3x += (float)v3[0]; a3y += (float)v3[1];
  }
  for (; e < dg; ++e) {
    bf16x2 v = *(const bf16x2*)(h + (size_t)nb[e] * D + off);
    a0x += (float)v[0]; a0y += (float)v[1];
  }
  a0x += a1x + a2x + a3x;
  a0y += a1y + a2y + a3y;
  bf16x2 o;
  o[0] = (bf16_t)a0x; o[1] = (bf16_t)a0y;
  *(bf16x2*)(z + (size_t)node * D + off) = o;
}

// ===========================================================================
// Cooperative: whole MLP of one layer.
//  P3: Y = z @ W1 + b1 (MFMA), BN column stats -> global atomics (Y dropped)
//  grid.sync
//  P4: BN coeffs; recompute Y (bit-identical), P=relu(a*Y+b), LDS transpose,
//      out = P @ W2 + b2 -> h' (bf16, relu) or final out (fp32)
// Grid-stride over tasks (782) — correct at any co-resident grid size.
// ===========================================================================
__global__ __launch_bounds__(256, 4) void mlp_layer(
    const bf16_t* __restrict__ zb, const bf16_t* __restrict__ Ws1,
    const bf16_t* __restrict__ Ws2, const float* __restrict__ b1l,
    const float* __restrict__ b2l, const float* __restrict__ gl,
    const float* __restrict__ btl, float* __restrict__ st,
    void* __restrict__ outp, int N, float invN, int last) {
  cg::grid_group grid = cg::this_grid();
  __shared__ bf16_t T[64][136];
  __shared__ float sred[256];
  __shared__ float abL[256];

  const int t = threadIdx.x;
  const int wv = t >> 6;
  const int lane = t & 63;
  const int l15 = lane & 15;
  const int quad = lane >> 4;
  const int nStrips = (N + 15) >> 4;
  const int nTasks = (nStrips + 3) >> 2;

  // ---- P3: GEMM1 -> stats ----
  sred[t] = 0.f;
  float sAcc[8], qAcc[8];
#pragma unroll
  for (int nt = 0; nt < 8; ++nt) { sAcc[nt] = 0.f; qAcc[nt] = 0.f; }

  for (int task = blockIdx.x; task < nTasks; task += gridDim.x) {
    const int strip = task * 4 + wv;
    if (strip < nStrips) {
      bf16x8 a[4];
      const int row = strip * 16 + l15;
      if (row < N) {
#pragma unroll
        for (int kc = 0; kc < 4; ++kc)
          a[kc] = *(const bf16x8*)(zb + (size_t)row * D + kc * 32 + quad * 8);
      } else {
#pragma unroll
        for (int kc = 0; kc < 4; ++kc)
#pragma unroll
          for (int j = 0; j < 8; ++j) a[kc][j] = (bf16_t)0.f;
      }
      floatx4 acc[8];
#pragma unroll
      for (int nt = 0; nt < 8; ++nt) {
        float bv = b1l[nt * 16 + l15];
        acc[nt] = (floatx4){bv, bv, bv, bv};
      }
#pragma unroll
      for (int nt = 0; nt < 8; ++nt) {
#pragma unroll
        for (int kc = 0; kc < 4; ++kc) {
          bf16x8 b = *(const bf16x8*)(Ws1 + (size_t)((nt * 4 + kc) * 64 + lane) * 8);
          acc[nt] = __builtin_amdgcn_mfma_f32_16x16x32_bf16(a[kc], b, acc[nt], 0, 0, 0);
        }
      }
      const int rowBase = strip * 16 + quad * 4;
#pragma unroll
      for (int nt = 0; nt < 8; ++nt) {
#pragma unroll
        for (int r = 0; r < 4; ++r) {
          if (rowBase + r < N) {
            float v = acc[nt][r];
            sAcc[nt] += v; qAcc[nt] += v * v;
          }
        }
      }
    }
  }
  __syncthreads();
#pragma unroll
  for (int nt = 0; nt < 8; ++nt) {
    float s = sAcc[nt], q = qAcc[nt];
    s += __shfl_xor(s, 16); s += __shfl_xor(s, 32);
    q += __shfl_xor(q, 16); q += __shfl_xor(q, 32);
    if (quad == 0) {
      int c = nt * 16 + l15;
      atomicAdd(&sred[c], s);
      atomicAdd(&sred[128 + c], q);
    }
  }
  __syncthreads();
  atomicAdd(&st[t], sred[t]);
  grid.sync();

  // ---- P4: BN coeffs + recompute + GEMM2 ----
  if (t < 128) {
    float mu = st[t] * invN;
    float var = fmaxf(st[128 + t] * invN - mu * mu, 0.f);
    float a = gl[t] * rsqrtf(var + BN_EPS);
    abL[t] = a;
    abL[128 + t] = btl[t] - mu * a;
  }
  __syncthreads();

  for (int task = blockIdx.x; task < nTasks; task += gridDim.x) {
    const int strip = task * 4 + wv;
    const bool active = strip < nStrips;
    if (active) {
      bf16x8 a[4];
      const int row = strip * 16 + l15;
      if (row < N) {
#pragma unroll
        for (int kc = 0; kc < 4; ++kc)
          a[kc] = *(const bf16x8*)(zb + (size_t)row * D + kc * 32 + quad * 8);
      } else {
#pragma unroll
        for (int kc = 0; kc < 4; ++kc)
#pragma unroll
          for (int j = 0; j < 8; ++j) a[kc][j] = (bf16_t)0.f;
      }
      floatx4 acc[8];
#pragma unroll
      for (int nt = 0; nt < 8; ++nt) {
        float bv = b1l[nt * 16 + l15];
        acc[nt] = (floatx4){bv, bv, bv, bv};
      }
#pragma unroll
      for (int nt = 0; nt < 8; ++nt) {
#pragma unroll
        for (int kc = 0; kc < 4; ++kc) {
          bf16x8 b = *(const bf16x8*)(Ws1 + (size_t)((nt * 4 + kc) * 64 + lane) * 8);
          acc[nt] = __builtin_amdgcn_mfma_f32_16x16x32_bf16(a[kc], b, acc[nt], 0, 0, 0);
        }
      }
      const int lr = wv * 16 + quad * 4;
#pragma unroll
      for (int nt = 0; nt < 8; ++nt) {
        int c = nt * 16 + l15;
        float av = abL[c], bv = abL[128 + c];
#pragma unroll
        for (int r = 0; r < 4; ++r)
          T[lr + r][c] = (bf16_t)fmaxf(fmaf(acc[nt][r], av, bv), 0.f);
      }
    }
    __syncthreads();
    if (active) {
      bf16x8 a2[4];
#pragma unroll
      for (int kc = 0; kc < 4; ++kc)
        a2[kc] = *(const bf16x8*)&T[wv * 16 + l15][kc * 32 + quad * 8];

      floatx4 acc2[8];
#pragma unroll
      for (int nt = 0; nt < 8; ++nt) {
        float bv = b2l[nt * 16 + l15];
        acc2[nt] = (floatx4){bv, bv, bv, bv};
      }
#pragma unroll
      for (int nt = 0; nt < 8; ++nt) {
#pragma unroll
        for (int kc = 0; kc < 4; ++kc) {
          bf16x8 b = *(const bf16x8*)(Ws2 + (size_t)((nt * 4 + kc) * 64 + lane) * 8);
          acc2[nt] = __builtin_amdgcn_mfma_f32_16x16x32_bf16(a2[kc], b, acc2[nt], 0, 0, 0);
        }
      }
      const int rowBase = strip * 16 + quad * 4;
      if (last) {
        float* out = (float*)outp;
#pragma unroll
        for (int nt = 0; nt < 8; ++nt) {
          int c = nt * 16 + l15;
#pragma unroll
          for (int r = 0; r < 4; ++r) {
            int row = rowBase + r;
            if (row < N) out[(size_t)row * D + c] = acc2[nt][r];
          }
        }
      } else {
        bf16_t* out = (bf16_t*)outp;
#pragma unroll
        for (int nt = 0; nt < 8; ++nt) {
          int c = nt * 16 + l15;
#pragma unroll
          for (int r = 0; r < 4; ++r) {
            int row = rowBase + r;
            if (row < N) out[(size_t)row * D + c] = (bf16_t)fmaxf(acc2[nt][r], 0.f);
          }
        }
      }
    }
    __syncthreads();
  }
}

// ===========================================================================
extern "C" void kernel_launch(void* const* d_in, const int* in_sizes, int n_in,
                              void* d_out, int out_size, void* d_ws, size_t ws_size,
                              hipStream_t stream) {
  const float* x     = (const float*)d_in[0];
  const float* W1    = (const float*)d_in[1];
  const float* b1    = (const float*)d_in[2];
  const float* gamma = (const float*)d_in[3];
  const float* beta  = (const float*)d_in[4];
  const float* W2    = (const float*)d_in[5];
  const float* b2    = (const float*)d_in[6];
  const int*   ei    = (const int*)d_in[7];

  int N = in_sizes[0] / D;
  int E = in_sizes[7] / 2;
  float* out = (float*)d_out;

  char* ws = (char*)d_ws;
  size_t bufBytes = (size_t)N * D * sizeof(bf16_t);        // 12.8 MB
  bf16_t* hb   = (bf16_t*)ws;
  bf16_t* zb   = (bf16_t*)(ws + bufBytes);
  unsigned short* ell = (unsigned short*)(ws + 2 * bufBytes);       // N*64 ushort
  int*    deg  = (int*)(ws + 2 * bufBytes + (size_t)N * ELLW * 2);  // N ints
  float*  stats = (float*)((char*)deg + (size_t)N * sizeof(int));   // 768 floats
  bf16_t* Wsw  = (bf16_t*)((char*)stats + 768 * sizeof(float));     // 6*16384 bf16

  float invN = 1.f / (float)N;                 // non-const: goes into args[]
  const int aggBlocks = (N + 3) / 4;

  // --- cooperative grids, clamped to queried co-residency ---
  int bpcPrep = 0, bpcMlp = 0;
  (void)hipOccupancyMaxActiveBlocksPerMultiprocessor(&bpcPrep, (const void*)prep_ell, 256, 0);
  (void)hipOccupancyMaxActiveBlocksPerMultiprocessor(&bpcMlp, (const void*)mlp_layer, 256, 0);
  if (bpcPrep < 1) bpcPrep = 1;
  if (bpcMlp < 1) bpcMlp = 1;
  int gridPrep = bpcPrep * 256; if (gridPrep > 2048) gridPrep = 2048;
  int nTasks = ((N + 15) / 16 + 3) / 4;
  int gridMlp = bpcMlp * 256; if (gridMlp > nTasks) gridMlp = nTasks;

  {
    void* args[] = {&x, &W1, &W2, &ei, &hb, &Wsw, &ell, &deg, &stats, &N, &E};
    (void)hipLaunchCooperativeKernel((const void*)prep_ell, dim3(gridPrep), dim3(256),
                                     args, 0, stream);
  }

  for (int i = 0; i < 3; ++i) {
    aggregate<<<aggBlocks, 256, 0, stream>>>(hb, zb, ell, deg, N);

    const bf16_t* Ws1 = Wsw + (size_t)i * 16384;
    const bf16_t* Ws2 = Wsw + (size_t)(i + 3) * 16384;
    const float* b1l = b1 + (size_t)i * D;
    const float* b2l = b2 + (size_t)i * D;
    const float* gl  = gamma + (size_t)i * D;
    const float* btl = beta + (size_t)i * D;
    float* st = stats + (size_t)i * 256;
    void* outp = (i == 2) ? (void*)out : (void*)hb;
    int last = (i == 2) ? 1 : 0;
    void* args[] = {&zb, &Ws1, &Ws2, &b1l, &b2l, &gl, &btl, &st,
                    &outp, &N, &invN, &last};
    (void)hipLaunchCooperativeKernel((const void*)mlp_layer, dim3(gridMlp), dim3(256),
                                     args, 0, stream);
  }
}

// Round 11
// 342.863 us; speedup vs baseline: 3.4463x; 2.1424x over previous
//
#include <hip/hip_runtime.h>

#define D 128
#define BN_EPS 1e-5f
#define ELLW 64             // max degree slots (Poisson(12.8): P(deg>64) ~ 1e-24)

typedef __bf16 bf16_t;
typedef __bf16 bf16x8 __attribute__((ext_vector_type(8)));
typedef __bf16 bf16x4 __attribute__((ext_vector_type(4)));
typedef __bf16 bf16x2 __attribute__((ext_vector_type(2)));
typedef float floatx4 __attribute__((ext_vector_type(4)));

// ===========================================================================
// prep: zero deg[N] + stats[768], x fp32 -> hb bf16, swizzle weights to
// MFMA B-frag order. Grid covers n4 = N*D/4 (largest range).
// ===========================================================================
__global__ void prep(const float* __restrict__ x, bf16_t* __restrict__ hb,
                     const float* __restrict__ W1, const float* __restrict__ W2,
                     bf16_t* __restrict__ Wsw, int* __restrict__ deg,
                     float* __restrict__ stats, int N, int n4) {
  int i = blockIdx.x * blockDim.x + threadIdx.x;
  if (i < n4) {
    float4 v = ((const float4*)x)[i];
    bf16x4 p;
    p[0] = (bf16_t)v.x; p[1] = (bf16_t)v.y; p[2] = (bf16_t)v.z; p[3] = (bf16_t)v.w;
    *(bf16x4*)(hb + (size_t)4 * i) = p;
  }
  if (i < N) deg[i] = 0;
  if (i < 768) stats[i] = 0.f;
  if (i < 6 * 16384) {
    // B-frag order: lane = quad*16 + (n&15) holds B[k=kc*32+quad*8+j][n]
    int mat = i >> 14;
    int kn = i & 16383;
    int k = kn >> 7;
    int n = kn & 127;
    const float* Wm = (mat < 3) ? (W1 + (size_t)mat * 16384)
                                : (W2 + (size_t)(mat - 3) * 16384);
    float v = Wm[kn];
    int f = ((n >> 4) << 2) | (k >> 5);
    int ln = (((k >> 3) & 3) << 4) | (n & 15);
    int j = k & 7;
    Wsw[(size_t)mat * 16384 + ((f << 6) + ln) * 8 + j] = (bf16_t)v;
  }
}

// ===========================================================================
// ell_fill: one-shot ELL build — atomic slot bump + native 4B scatter.
// (int32 entries: sub-word stores proved pathological in R10.)
// ===========================================================================
__global__ void ell_fill(const int* __restrict__ src, const int* __restrict__ dst,
                         int* __restrict__ deg, int* __restrict__ ell, int E) {
  int e = blockIdx.x * blockDim.x + threadIdx.x;
  if (e < E) {
    int d = dst[e];
    int slot = atomicAdd(&deg[d], 1);
    if (slot < ELLW) ell[(size_t)d * ELLW + slot] = src[e];
  }
}

// ===========================================================================
// aggregate: z[v] = h[v] + sum_{u in N(v)} h[u] — one wave per node
// (12500 blocks; oversubscription is mandatory for this gather: R5/R8).
// ===========================================================================
__global__ __launch_bounds__(256) void aggregate(
    const bf16_t* __restrict__ h, bf16_t* __restrict__ z,
    const int* __restrict__ ell, const int* __restrict__ deg, int Nn) {
  int node = blockIdx.x * 4 + (threadIdx.x >> 6);
  if (node >= Nn) return;
  int lane = threadIdx.x & 63;
  int off = lane << 1;
  int dg = deg[node]; if (dg > ELLW) dg = ELLW;
  const int* nb = ell + (size_t)node * ELLW;

  bf16x2 sv = *(const bf16x2*)(h + (size_t)node * D + off);
  float a0x = (float)sv[0], a0y = (float)sv[1];
  float a1x = 0.f, a1y = 0.f, a2x = 0.f, a2y = 0.f, a3x = 0.f, a3y = 0.f;
  int e = 0;
  for (; e + 4 <= dg; e += 4) {
    int4 i4 = *(const int4*)(nb + e);
    bf16x2 v0 = *(const bf16x2*)(h + (size_t)i4.x * D + off);
    bf16x2 v1 = *(const bf16x2*)(h + (size_t)i4.y * D + off);
    bf16x2 v2 = *(const bf16x2*)(h + (size_t)i4.z * D + off);
    bf16x2 v3 = *(const bf16x2*)(h + (size_t)i4.w * D + off);
    a0x += (float)v0[0]; a0y += (float)v0[1];
    a1x += (float)v1[0]; a1y += (float)v1[1];
    a2x += (float)v2[0]; a2y += (float)v2[1];
    a3x += (float)v3[0]; a3y += (float)v3[1];
  }
  for (; e < dg; ++e) {
    bf16x2 v = *(const bf16x2*)(h + (size_t)nb[e] * D + off);
    a0x += (float)v[0]; a0y += (float)v[1];
  }
  a0x += a1x + a2x + a3x;
  a0y += a1y + a2y + a3y;
  bf16x2 o;
  o[0] = (bf16_t)a0x; o[1] = (bf16_t)a0y;
  *(bf16x2*)(z + (size_t)node * D + off) = o;
}

// ===========================================================================
// gemm1_stats: Y = Z @ W1 + b1 (bf16 MFMA). Z A-frags direct from global
// (row-major bf16 == A-frag order). Emits BN stats; stores Y in A-frag order
// for mlp2 (LDS transpose). Block 256 = 4 waves, wave = one 16-row strip.
// ===========================================================================
__global__ __launch_bounds__(256) void gemm1_stats(
    const bf16_t* __restrict__ Z, const bf16_t* __restrict__ Wsw,
    const float* __restrict__ bias, bf16_t* __restrict__ Yf,
    float* __restrict__ stats, int nStrips, int N) {
  __shared__ bf16_t T[64][136];
  __shared__ float sred[256];
  const int t = threadIdx.x;
  const int wv = t >> 6;
  const int lane = t & 63;
  const int l15 = lane & 15;
  const int quad = lane >> 4;
  const int strip = blockIdx.x * 4 + wv;
  const bool active = strip < nStrips;

  sred[t] = 0.f;

  bf16x8 a[4];
  const int row = strip * 16 + l15;
  if (active && row < N) {
#pragma unroll
    for (int kc = 0; kc < 4; ++kc)
      a[kc] = *(const bf16x8*)(Z + (size_t)row * D + kc * 32 + quad * 8);
  } else {
#pragma unroll
    for (int kc = 0; kc < 4; ++kc)
#pragma unroll
      for (int j = 0; j < 8; ++j) a[kc][j] = (bf16_t)0.f;
  }

  floatx4 acc[8];
#pragma unroll
  for (int nt = 0; nt < 8; ++nt) {
    float bv = bias[nt * 16 + l15];
    acc[nt] = (floatx4){bv, bv, bv, bv};
  }

#pragma unroll
  for (int nt = 0; nt < 8; ++nt) {
#pragma unroll
    for (int kc = 0; kc < 4; ++kc) {
      bf16x8 b = *(const bf16x8*)(Wsw + (size_t)((nt * 4 + kc) * 64 + lane) * 8);
      acc[nt] = __builtin_amdgcn_mfma_f32_16x16x32_bf16(a[kc], b, acc[nt], 0, 0, 0);
    }
  }

  // transpose C-layout -> A-frag order via LDS
  const int lr = wv * 16 + quad * 4;
#pragma unroll
  for (int nt = 0; nt < 8; ++nt) {
    int c = nt * 16 + l15;
#pragma unroll
    for (int r = 0; r < 4; ++r) T[lr + r][c] = (bf16_t)acc[nt][r];
  }
  __syncthreads();
  if (active) {
#pragma unroll
    for (int kc = 0; kc < 4; ++kc) {
      bf16x8 yv = *(const bf16x8*)&T[wv * 16 + l15][kc * 32 + quad * 8];
      *(bf16x8*)(Yf + ((size_t)(strip * 4 + kc) * 64 + lane) * 8) = yv;
    }
  }

  // BN stats: C/D layout col = nt*16+l15, row = quad*4+r
  const int rowBase = strip * 16 + quad * 4;
#pragma unroll
  for (int nt = 0; nt < 8; ++nt) {
    int c = nt * 16 + l15;
    float s = 0.f, q = 0.f;
    if (active) {
#pragma unroll
      for (int r = 0; r < 4; ++r) {
        if (rowBase + r < N) {
          float v = acc[nt][r];
          s += v; q += v * v;
        }
      }
    }
    s += __shfl_xor(s, 16); s += __shfl_xor(s, 32);
    q += __shfl_xor(q, 16); q += __shfl_xor(q, 32);
    if (quad == 0) {
      atomicAdd(&sred[c], s);
      atomicAdd(&sred[128 + c], q);
    }
  }
  __syncthreads();
  atomicAdd(&stats[t], sred[t]);
}

// ===========================================================================
// mlp2: BN coeffs from stats -> load Y A-frags -> BN+ReLU in-fragment
// (per-column) -> GEMM2 -> maybe_relu -> h' (bf16) or out (fp32).
// ===========================================================================
__global__ __launch_bounds__(256) void mlp2(
    const bf16_t* __restrict__ Yf, const float* __restrict__ stats,
    const float* __restrict__ gamma, const float* __restrict__ beta,
    const bf16_t* __restrict__ Wsw, const float* __restrict__ bias,
    void* __restrict__ outp, int nStrips, int N, float invN,
    int relu_out, int fp32_out) {
  __shared__ float abL[256];
  const int t = threadIdx.x;
  if (t < 128) {
    float mu = stats[t] * invN;
    float var = fmaxf(stats[128 + t] * invN - mu * mu, 0.f);
    float a = gamma[t] * rsqrtf(var + BN_EPS);
    abL[t] = a;
    abL[128 + t] = beta[t] - mu * a;
  }
  __syncthreads();

  const int wv = t >> 6;
  const int lane = t & 63;
  const int l15 = lane & 15;
  const int quad = lane >> 4;
  const int strip = blockIdx.x * 4 + wv;
  if (strip >= nStrips) return;

  bf16x8 a2[4];
#pragma unroll
  for (int kc = 0; kc < 4; ++kc) {
    bf16x8 y = *(const bf16x8*)(Yf + ((size_t)(strip * 4 + kc) * 64 + lane) * 8);
#pragma unroll
    for (int j = 0; j < 8; ++j) {
      int c = kc * 32 + quad * 8 + j;
      float v = fmaxf(fmaf((float)y[j], abL[c], abL[128 + c]), 0.f);
      a2[kc][j] = (bf16_t)v;
    }
  }

  floatx4 acc[8];
#pragma unroll
  for (int nt = 0; nt < 8; ++nt) {
    float bv = bias[nt * 16 + l15];
    acc[nt] = (floatx4){bv, bv, bv, bv};
  }

#pragma unroll
  for (int nt = 0; nt < 8; ++nt) {
#pragma unroll
    for (int kc = 0; kc < 4; ++kc) {
      bf16x8 b = *(const bf16x8*)(Wsw + (size_t)((nt * 4 + kc) * 64 + lane) * 8);
      acc[nt] = __builtin_amdgcn_mfma_f32_16x16x32_bf16(a2[kc], b, acc[nt], 0, 0, 0);
    }
  }

  const int rowBase = strip * 16 + quad * 4;
  if (fp32_out) {
    float* out = (float*)outp;
#pragma unroll
    for (int nt = 0; nt < 8; ++nt) {
      int c = nt * 16 + l15;
#pragma unroll
      for (int r = 0; r < 4; ++r) {
        int row = rowBase + r;
        if (row < N) {
          float v = acc[nt][r];
          if (relu_out) v = fmaxf(v, 0.f);
          out[(size_t)row * D + c] = v;
        }
      }
    }
  } else {
    bf16_t* out = (bf16_t*)outp;
#pragma unroll
    for (int nt = 0; nt < 8; ++nt) {
      int c = nt * 16 + l15;
#pragma unroll
      for (int r = 0; r < 4; ++r) {
        int row = rowBase + r;
        if (row < N) {
          float v = acc[nt][r];
          if (relu_out) v = fmaxf(v, 0.f);
          out[(size_t)row * D + c] = (bf16_t)v;
        }
      }
    }
  }
}

// ===========================================================================
extern "C" void kernel_launch(void* const* d_in, const int* in_sizes, int n_in,
                              void* d_out, int out_size, void* d_ws, size_t ws_size,
                              hipStream_t stream) {
  const float* x     = (const float*)d_in[0];
  const float* W1    = (const float*)d_in[1];
  const float* b1    = (const float*)d_in[2];
  const float* gamma = (const float*)d_in[3];
  const float* beta  = (const float*)d_in[4];
  const float* W2    = (const float*)d_in[5];
  const float* b2    = (const float*)d_in[6];
  const int*   ei    = (const int*)d_in[7];

  const int N = in_sizes[0] / D;
  const int E = in_sizes[7] / 2;
  const int* src = ei;
  const int* dst = ei + E;
  float* out = (float*)d_out;

  char* ws = (char*)d_ws;
  size_t bufBytes = (size_t)N * D * sizeof(bf16_t);        // 12.8 MB
  bf16_t* hb   = (bf16_t*)ws;                               // h (bf16)
  bf16_t* zb   = (bf16_t*)(ws + bufBytes);                  // z (bf16)
  bf16_t* Yf   = (bf16_t*)(ws + 2 * bufBytes);              // Y in A-frag order
  int*    ell  = (int*)(ws + 3 * bufBytes);                 // N*64 int = 12.8 MB
  int*    deg  = (int*)((char*)ell + (size_t)N * ELLW * sizeof(int));
  float*  stats = (float*)((char*)deg + (size_t)N * sizeof(int));   // 768 floats
  bf16_t* Wsw  = (bf16_t*)((char*)stats + 768 * sizeof(float));     // 6*16384 bf16

  const int n4 = N * D / 4;
  const int prepBlocks = (n4 + 255) / 256;
  const int eb = (E + 255) / 256;
  const int aggBlocks = (N + 3) / 4;
  const int nStrips = (N + 15) / 16;
  const int gemmBlocks = (nStrips + 3) / 4;
  const float invN = 1.f / (float)N;

  prep<<<prepBlocks, 256, 0, stream>>>(x, hb, W1, W2, Wsw, deg, stats, N, n4);
  ell_fill<<<eb, 256, 0, stream>>>(src, dst, deg, ell, E);

  for (int i = 0; i < 3; ++i) {
    float* st = stats + (size_t)i * 256;
    aggregate<<<aggBlocks, 256, 0, stream>>>(hb, zb, ell, deg, N);
    gemm1_stats<<<gemmBlocks, 256, 0, stream>>>(
        zb, Wsw + (size_t)i * 16384, b1 + (size_t)i * D, Yf, st, nStrips, N);
    void* Ob = (i == 2) ? d_out : (void*)hb;
    mlp2<<<gemmBlocks, 256, 0, stream>>>(
        Yf, st, gamma + (size_t)i * D, beta + (size_t)i * D,
        Wsw + (size_t)(i + 3) * 16384, b2 + (size_t)i * D,
        Ob, nStrips, N, invN, (i < 2) ? 1 : 0, (i == 2) ? 1 : 0);
  }
}